// Round 2
// baseline (2468.469 us; speedup 1.0000x reference)
//
#include <hip/hip_runtime.h>
#include <hip/hip_bf16.h>

// Problem constants (fixed by reference setup_inputs)
constexpr int kC  = 20;              // NUM_CLASSES
constexpr int kP  = 8192;            // NUM_PARCELS
constexpr int kIgnore = 255;         // IGNORE_INDEX
constexpr int kHW = 512 * 512;       // H*W = 262144 = 2^18
constexpr int kN  = 8;
constexpr int kM  = kN * kHW;        // 2097152 pixels

// Workspace layout (bytes):
//   seg   : kP*kC floats   = 655360
//   cnt   : kP floats      =  32768
//   first : kP ints        =  32768
//   accum : 2 floats
constexpr size_t kSegBytes   = (size_t)kP * kC * sizeof(float);
constexpr size_t kCntBytes   = (size_t)kP * sizeof(float);
constexpr size_t kFirstBytes = (size_t)kP * sizeof(int);

__global__ __launch_bounds__(256)
void init_ws(float* __restrict__ seg, float* __restrict__ cnt,
             int* __restrict__ first, float* __restrict__ accum) {
    int i = blockIdx.x * blockDim.x + threadIdx.x;
    if (i < kP * kC) seg[i] = 0.0f;
    if (i < kP) { cnt[i] = 0.0f; first[i] = kM; }
    if (i < 2) accum[i] = 0.0f;
}

__global__ __launch_bounds__(256)
void scatter(const float* __restrict__ pred,
             const int* __restrict__ target,
             const int* __restrict__ parcel,
             float* __restrict__ seg,
             float* __restrict__ cnt,
             int* __restrict__ first) {
    const int stride = gridDim.x * blockDim.x;
    for (int idx = blockIdx.x * blockDim.x + threadIdx.x; idx < kM; idx += stride) {
        const int t = target[idx];
        const int p = parcel[idx];
        if (t == kIgnore) continue;
        const int n  = idx >> 18;          // idx / kHW
        const int hw = idx & (kHW - 1);    // idx % kHW
        const float* base = pred + (size_t)n * kC * kHW + hw;
        float v[kC];
#pragma unroll
        for (int c = 0; c < kC; ++c) v[c] = base[(size_t)c * kHW];
        float* srow = seg + p * kC;
#pragma unroll
        for (int c = 0; c < kC; ++c) atomicAdd(&srow[c], v[c]);
        atomicAdd(&cnt[p], 1.0f);
        atomicMin(&first[p], idx);
    }
}

__global__ __launch_bounds__(256)
void finalize(const float* __restrict__ seg,
              const float* __restrict__ cnt,
              const int* __restrict__ first,
              const int* __restrict__ target,
              const int* __restrict__ cls_num,
              float* __restrict__ accum) {
    __shared__ float logcls[kC];
    if (threadIdx.x < kC) logcls[threadIdx.x] = logf((float)cls_num[threadIdx.x]);
    __syncthreads();

    const int p = blockIdx.x * blockDim.x + threadIdx.x;
    float nll = 0.0f, pres = 0.0f;
    if (p < kP) {
        const float c = cnt[p];
        if (c > 0.0f) {
            int f = first[p];
            if (f > kM - 1) f = kM - 1;
            const int label = target[f];
            const float inv = 1.0f / c;
            float bal[kC];
            float m = -3.402823466e38f;
#pragma unroll
            for (int k = 0; k < kC; ++k) {
                bal[k] = seg[p * kC + k] * inv + logcls[k];
                m = fmaxf(m, bal[k]);
            }
            float s = 0.0f;
#pragma unroll
            for (int k = 0; k < kC; ++k) s += expf(bal[k] - m);
            const float lse = m + logf(s);
            pres = 1.0f;
            if (label >= 0 && label < kC) nll = lse - bal[label];
        }
    }

    // block reduction: wave64 shuffle then cross-wave via LDS
    float a = nll, b = pres;
#pragma unroll
    for (int off = 32; off > 0; off >>= 1) {
        a += __shfl_down(a, off);
        b += __shfl_down(b, off);
    }
    __shared__ float wsum[4], wcnt[4];
    const int lane = threadIdx.x & 63;
    const int wid  = threadIdx.x >> 6;
    if (lane == 0) { wsum[wid] = a; wcnt[wid] = b; }
    __syncthreads();
    if (threadIdx.x == 0) {
        float sa = 0.0f, sb = 0.0f;
        for (int w = 0; w < 4; ++w) { sa += wsum[w]; sb += wcnt[w]; }
        atomicAdd(&accum[0], sa);
        atomicAdd(&accum[1], sb);
    }
}

__global__ void write_out(const float* __restrict__ accum, float* __restrict__ out) {
    out[0] = accum[0] / fmaxf(accum[1], 1.0f);
}

extern "C" void kernel_launch(void* const* d_in, const int* in_sizes, int n_in,
                              void* d_out, int out_size, void* d_ws, size_t ws_size,
                              hipStream_t stream) {
    const float* pred    = (const float*)d_in[0];
    const int*   target  = (const int*)d_in[1];
    const int*   parcel  = (const int*)d_in[2];
    const int*   cls_num = (const int*)d_in[3];

    char* ws = (char*)d_ws;
    float* seg   = (float*)(ws);
    float* cnt   = (float*)(ws + kSegBytes);
    int*   first = (int*)(ws + kSegBytes + kCntBytes);
    float* accum = (float*)(ws + kSegBytes + kCntBytes + kFirstBytes);

    init_ws<<<(kP * kC + 255) / 256, 256, 0, stream>>>(seg, cnt, first, accum);
    scatter<<<2048, 256, 0, stream>>>(pred, target, parcel, seg, cnt, first);
    finalize<<<kP / 256, 256, 0, stream>>>(seg, cnt, first, target, cls_num, accum);
    write_out<<<1, 1, 0, stream>>>(accum, (float*)d_out);
}

// Round 3
// 633.213 us; speedup vs baseline: 3.8983x; 3.8983x over previous
//
#include <hip/hip_runtime.h>
#include <hip/hip_bf16.h>

constexpr int kC  = 20;              // NUM_CLASSES
constexpr int kP  = 8192;            // NUM_PARCELS
constexpr int kIgnore = 255;         // IGNORE_INDEX
constexpr int kHW = 512 * 512;       // H*W = 2^18
constexpr int kN  = 8;
constexpr int kM  = kN * kHW;        // 2097152 pixels
constexpr int NB  = 256;             // scatter blocks (chunks)
constexpr int CH  = kM / NB;         // 8192 pixels per chunk

// ---- sort-pipeline workspace layout (bytes) ----
constexpr size_t oHist  = 0;                                   // NB*kP*4 = 8 MB
constexpr size_t oMinb  = oHist + (size_t)NB * kP * 4;         // 8 MB
constexpr size_t oOff   = oMinb + (size_t)NB * kP * 4;         // 8 MB
constexpr size_t oCnt   = oOff  + (size_t)NB * kP * 4;         // 32 KB
constexpr size_t oFirst = oCnt  + (size_t)kP * 4;              // 32 KB
constexpr size_t oBin   = oFirst + (size_t)kP * 4;             // 32 KB
constexpr size_t oAcc   = oBin  + (size_t)kP * 4;              // 256 B pad
constexpr size_t oSort  = oAcc + 256;
constexpr size_t kNeedIndex  = oSort + (size_t)kM * 4;               // ~33.7 MB
constexpr size_t kNeedValues = oSort + (size_t)kM * kC * 4;          // ~193 MB

// ================= sort pipeline =================

__global__ __launch_bounds__(256)
void k1_hist(const int* __restrict__ target, const int* __restrict__ parcel,
             int* __restrict__ hist, int* __restrict__ minb) {
    __shared__ int lh[kP];
    __shared__ int lm[kP];
    const int b = blockIdx.x;
    for (int p = threadIdx.x; p < kP; p += 256) { lh[p] = 0; lm[p] = kM; }
    __syncthreads();
    const int base = b * CH;
    for (int j = threadIdx.x; j < CH; j += 256) {
        const int i = base + j;
        const int t = target[i];
        if (t != kIgnore) {
            const int p = parcel[i];
            atomicAdd(&lh[p], 1);
            atomicMin(&lm[p], i);
        }
    }
    __syncthreads();
    int* hb = hist + (size_t)b * kP;
    int* mb = minb + (size_t)b * kP;
    for (int p = threadIdx.x; p < kP; p += 256) { hb[p] = lh[p]; mb[p] = lm[p]; }
}

__global__ __launch_bounds__(256)
void k2_colscan(const int* __restrict__ hist, const int* __restrict__ minb,
                int* __restrict__ off, int* __restrict__ cnt, int* __restrict__ first) {
    const int p = blockIdx.x * 256 + threadIdx.x;   // 32 blocks cover kP
    int run = 0, mn = kM;
    for (int b = 0; b < NB; ++b) {
        const size_t o = (size_t)b * kP + p;
        const int h = hist[o];
        off[o] = run;
        run += h;
        mn = min(mn, minb[o]);
    }
    cnt[p] = run;
    first[p] = mn;
}

__global__ __launch_bounds__(256)
void k3_scan(const int* __restrict__ cnt, int* __restrict__ binstart,
             float* __restrict__ accum) {
    __shared__ int part[256];
    const int t = threadIdx.x;
    constexpr int seg = kP / 256;   // 32
    int loc[seg];
    int s = 0;
    const int base = t * seg;
#pragma unroll
    for (int j = 0; j < seg; ++j) { loc[j] = s; s += cnt[base + j]; }
    part[t] = s;
    __syncthreads();
    if (t == 0) {
        int r = 0;
        for (int i = 0; i < 256; ++i) { const int v = part[i]; part[i] = r; r += v; }
    }
    __syncthreads();
    const int pb = part[t];
#pragma unroll
    for (int j = 0; j < seg; ++j) binstart[base + j] = pb + loc[j];
    if (t == 0) { accum[0] = 0.0f; accum[1] = 0.0f; }
}

template <bool VALUES>
__global__ __launch_bounds__(256)
void k5_scatter(const int* __restrict__ target, const int* __restrict__ parcel,
                const float* __restrict__ pred,
                const int* __restrict__ off, const int* __restrict__ binstart,
                float* __restrict__ sortedV, int* __restrict__ sortedIdx) {
    __shared__ int cur[kP];
    const int b = blockIdx.x;
    const int* ob = off + (size_t)b * kP;
    for (int p = threadIdx.x; p < kP; p += 256) cur[p] = binstart[p] + ob[p];
    __syncthreads();
    const int base = b * CH;
    for (int j = threadIdx.x; j < CH; j += 256) {
        const int i = base + j;
        const int t = target[i];
        if (t == kIgnore) continue;
        const int p = parcel[i];
        const int pos = atomicAdd(&cur[p], 1);   // LDS atomic, block-local
        if (VALUES) {
            const int n = i >> 18, hw = i & (kHW - 1);
            const float* pr = pred + (size_t)n * kC * kHW + hw;
            float v[kC];
#pragma unroll
            for (int c = 0; c < kC; ++c) v[c] = pr[(size_t)c * kHW];
            float* dst = sortedV + (size_t)pos * kC;   // 80B rows, 16B-aligned
#pragma unroll
            for (int q = 0; q < 5; ++q) {
                *reinterpret_cast<float4*>(dst + 4 * q) =
                    make_float4(v[4*q], v[4*q+1], v[4*q+2], v[4*q+3]);
            }
        } else {
            sortedIdx[pos] = i;
        }
    }
}

template <bool VALUES>
__global__ __launch_bounds__(64)
void k6_loss(const float* __restrict__ sortedV, const int* __restrict__ sortedIdx,
             const float* __restrict__ pred,
             const int* __restrict__ binstart, const int* __restrict__ cnt,
             const int* __restrict__ first, const int* __restrict__ target,
             const int* __restrict__ cls_num, float* __restrict__ accum) {
    const int p = blockIdx.x;
    const int lane = threadIdx.x;
    const int c0 = binstart[p];
    const int n  = cnt[p];
    float acc[kC];
#pragma unroll
    for (int c = 0; c < kC; ++c) acc[c] = 0.0f;
    if (VALUES) {
        const float* basev = sortedV + (size_t)c0 * kC;
        for (int r = lane; r < n; r += 64) {
            const float* row = basev + (size_t)r * kC;
#pragma unroll
            for (int q = 0; q < 5; ++q) {
                const float4 f4 = *reinterpret_cast<const float4*>(row + 4 * q);
                acc[4*q] += f4.x; acc[4*q+1] += f4.y; acc[4*q+2] += f4.z; acc[4*q+3] += f4.w;
            }
        }
    } else {
        for (int r = lane; r < n; r += 64) {
            const int i = sortedIdx[c0 + r];
            const int nn = i >> 18, hw = i & (kHW - 1);
            const float* pr = pred + (size_t)nn * kC * kHW + hw;
#pragma unroll
            for (int c = 0; c < kC; ++c) acc[c] += pr[(size_t)c * kHW];
        }
    }
#pragma unroll
    for (int c = 0; c < kC; ++c) {
        float v = acc[c];
#pragma unroll
        for (int o = 32; o > 0; o >>= 1) v += __shfl_xor(v, o);
        acc[c] = v;
    }
    if (lane == 0 && n > 0) {
        int f = first[p]; if (f > kM - 1) f = kM - 1;
        const int label = target[f];
        const float inv = 1.0f / (float)n;
        float bal[kC];
        float m = -3.402823466e38f;
#pragma unroll
        for (int c = 0; c < kC; ++c) {
            bal[c] = acc[c] * inv + logf((float)cls_num[c]);
            m = fmaxf(m, bal[c]);
        }
        float s = 0.0f;
#pragma unroll
        for (int c = 0; c < kC; ++c) s += expf(bal[c] - m);
        const float lse = m + logf(s);
        float nll = 0.0f;
        if (label >= 0 && label < kC) nll = lse - bal[label];
        atomicAdd(&accum[0], nll);
        atomicAdd(&accum[1], 1.0f);
    }
}

__global__ void k7_out(const float* __restrict__ accum, float* __restrict__ out) {
    out[0] = accum[0] / fmaxf(accum[1], 1.0f);
}

// ================= atomic fallback (proven-correct round-0 path) =================

__global__ __launch_bounds__(256)
void fb_init(float* __restrict__ seg, float* __restrict__ cnt,
             int* __restrict__ first, float* __restrict__ accum) {
    const int i = blockIdx.x * blockDim.x + threadIdx.x;
    if (i < kP * kC) seg[i] = 0.0f;
    if (i < kP) { cnt[i] = 0.0f; first[i] = kM; }
    if (i < 2) accum[i] = 0.0f;
}

__global__ __launch_bounds__(256)
void fb_scatter(const float* __restrict__ pred, const int* __restrict__ target,
                const int* __restrict__ parcel, float* __restrict__ seg,
                float* __restrict__ cnt, int* __restrict__ first) {
    const int stride = gridDim.x * blockDim.x;
    for (int idx = blockIdx.x * blockDim.x + threadIdx.x; idx < kM; idx += stride) {
        const int t = target[idx];
        const int p = parcel[idx];
        if (t == kIgnore) continue;
        const int n = idx >> 18, hw = idx & (kHW - 1);
        const float* base = pred + (size_t)n * kC * kHW + hw;
        float* srow = seg + p * kC;
#pragma unroll
        for (int c = 0; c < kC; ++c) atomicAdd(&srow[c], base[(size_t)c * kHW]);
        atomicAdd(&cnt[p], 1.0f);
        atomicMin(&first[p], idx);
    }
}

__global__ __launch_bounds__(256)
void fb_finalize(const float* __restrict__ seg, const float* __restrict__ cnt,
                 const int* __restrict__ first, const int* __restrict__ target,
                 const int* __restrict__ cls_num, float* __restrict__ accum) {
    __shared__ float logcls[kC];
    if (threadIdx.x < kC) logcls[threadIdx.x] = logf((float)cls_num[threadIdx.x]);
    __syncthreads();
    const int p = blockIdx.x * blockDim.x + threadIdx.x;
    float nll = 0.0f, pres = 0.0f;
    if (p < kP) {
        const float c = cnt[p];
        if (c > 0.0f) {
            int f = first[p]; if (f > kM - 1) f = kM - 1;
            const int label = target[f];
            const float inv = 1.0f / c;
            float bal[kC]; float m = -3.402823466e38f;
#pragma unroll
            for (int k = 0; k < kC; ++k) {
                bal[k] = seg[p * kC + k] * inv + logcls[k];
                m = fmaxf(m, bal[k]);
            }
            float s = 0.0f;
#pragma unroll
            for (int k = 0; k < kC; ++k) s += expf(bal[k] - m);
            const float lse = m + logf(s);
            pres = 1.0f;
            if (label >= 0 && label < kC) nll = lse - bal[label];
        }
    }
    float a = nll, b = pres;
#pragma unroll
    for (int o = 32; o > 0; o >>= 1) { a += __shfl_down(a, o); b += __shfl_down(b, o); }
    __shared__ float wsum[4], wcnt[4];
    const int lane = threadIdx.x & 63, wid = threadIdx.x >> 6;
    if (lane == 0) { wsum[wid] = a; wcnt[wid] = b; }
    __syncthreads();
    if (threadIdx.x == 0) {
        float sa = 0.0f, sb = 0.0f;
        for (int w = 0; w < 4; ++w) { sa += wsum[w]; sb += wcnt[w]; }
        atomicAdd(&accum[0], sa);
        atomicAdd(&accum[1], sb);
    }
}

// ================= launch =================

extern "C" void kernel_launch(void* const* d_in, const int* in_sizes, int n_in,
                              void* d_out, int out_size, void* d_ws, size_t ws_size,
                              hipStream_t stream) {
    const float* pred    = (const float*)d_in[0];
    const int*   target  = (const int*)d_in[1];
    const int*   parcel  = (const int*)d_in[2];
    const int*   cls_num = (const int*)d_in[3];
    char* ws = (char*)d_ws;

    if (ws_size >= kNeedIndex) {
        int*   hist     = (int*)(ws + oHist);
        int*   minb     = (int*)(ws + oMinb);
        int*   off      = (int*)(ws + oOff);
        int*   cnt      = (int*)(ws + oCnt);
        int*   first    = (int*)(ws + oFirst);
        int*   binstart = (int*)(ws + oBin);
        float* accum    = (float*)(ws + oAcc);
        float* sortedV  = (float*)(ws + oSort);
        int*   sortedI  = (int*)(ws + oSort);

        k1_hist<<<NB, 256, 0, stream>>>(target, parcel, hist, minb);
        k2_colscan<<<kP / 256, 256, 0, stream>>>(hist, minb, off, cnt, first);
        k3_scan<<<1, 256, 0, stream>>>(cnt, binstart, accum);
        if (ws_size >= kNeedValues) {
            k5_scatter<true><<<NB, 256, 0, stream>>>(target, parcel, pred, off, binstart, sortedV, sortedI);
            k6_loss<true><<<kP, 64, 0, stream>>>(sortedV, sortedI, pred, binstart, cnt, first, target, cls_num, accum);
        } else {
            k5_scatter<false><<<NB, 256, 0, stream>>>(target, parcel, pred, off, binstart, sortedV, sortedI);
            k6_loss<false><<<kP, 64, 0, stream>>>(sortedV, sortedI, pred, binstart, cnt, first, target, cls_num, accum);
        }
        k7_out<<<1, 1, 0, stream>>>(accum, (float*)d_out);
    } else {
        // atomic fallback (tiny ws)
        float* seg   = (float*)(ws);
        float* cnt   = (float*)(ws + (size_t)kP * kC * 4);
        int*   first = (int*)(ws + (size_t)kP * kC * 4 + (size_t)kP * 4);
        float* accum = (float*)(ws + (size_t)kP * kC * 4 + (size_t)kP * 8);
        fb_init<<<(kP * kC + 255) / 256, 256, 0, stream>>>(seg, cnt, first, accum);
        fb_scatter<<<2048, 256, 0, stream>>>(pred, target, parcel, seg, cnt, first);
        fb_finalize<<<kP / 256, 256, 0, stream>>>(seg, cnt, first, target, cls_num, accum);
        k7_out<<<1, 1, 0, stream>>>(accum, (float*)d_out);
    }
}

// Round 4
// 409.318 us; speedup vs baseline: 6.0307x; 1.5470x over previous
//
#include <hip/hip_runtime.h>
#include <hip/hip_bf16.h>

constexpr int kC  = 20;              // NUM_CLASSES
constexpr int kP  = 8192;            // NUM_PARCELS
constexpr int kIgnore = 255;         // IGNORE_INDEX
constexpr int kHW = 512 * 512;       // H*W = 2^18
constexpr int kM  = 8 * kHW;         // 2097152 pixels
constexpr int NB  = 256;             // chunks
constexpr int CH  = kM / NB;         // 8192 pixels per chunk

// ---- workspace layout (bytes) ----
// off (hist in-place) | cnt | first | bin | accum | parcelAcc | [minb / sortedV alias]
constexpr size_t oOff   = 0;                                  // NB*kP*4 = 8 MB
constexpr size_t oCnt   = oOff  + (size_t)NB * kP * 4;
constexpr size_t oFirst = oCnt  + (size_t)kP * 4;
constexpr size_t oBin   = oFirst + (size_t)kP * 4;
constexpr size_t oAcc   = oBin  + (size_t)kP * 4;
constexpr size_t oPAcc  = oAcc  + 256;
constexpr size_t oMinb  = oPAcc + (size_t)kP * kC * 4;        // 8 MB, dead after k2
constexpr size_t oSort  = oMinb;                              // sortedV aliases minb
constexpr size_t needCB(int cb) { return oSort + (size_t)kM * cb * 2; }
constexpr size_t kNeed20 = oSort + (size_t)kM * 20 * 2;       // ~92.7 MB
constexpr size_t kNeed10 = oSort + (size_t)kM * 10 * 2;       // ~50.7 MB
constexpr size_t kNeed4  = oSort + (size_t)kM * 4 * 2;        // ~25.5 MB

__device__ inline unsigned bf16rne(float x) {
    unsigned u = __float_as_uint(x);
    return (u + 0x7fffu + ((u >> 16) & 1u)) >> 16;   // round-to-nearest-even, no NaN in data
}

// ---- k1: per-chunk histogram + per-chunk min pixel index ----
__global__ __launch_bounds__(256)
void k1_hist(const int* __restrict__ target, const int* __restrict__ parcel,
             int* __restrict__ hist, int* __restrict__ minb) {
    __shared__ int lh[kP];
    __shared__ int lm[kP];
    const int b = blockIdx.x;
    for (int p = threadIdx.x; p < kP; p += 256) { lh[p] = 0; lm[p] = kM; }
    __syncthreads();
    const int base = b * CH;
    for (int j = threadIdx.x; j < CH; j += 256) {
        const int i = base + j;
        if (target[i] != kIgnore) {
            const int p = parcel[i];
            atomicAdd(&lh[p], 1);
            atomicMin(&lm[p], i);
        }
    }
    __syncthreads();
    int* hb = hist + (size_t)b * kP;
    int* mb = minb + (size_t)b * kP;
    for (int p = threadIdx.x; p < kP; p += 256) { hb[p] = lh[p]; mb[p] = lm[p]; }
}

// ---- k2: column scan over chunks; hist -> off in place ----
__global__ __launch_bounds__(256)
void k2_colscan(int* __restrict__ histoff, const int* __restrict__ minb,
                int* __restrict__ cnt, int* __restrict__ first) {
    const int p = blockIdx.x * 256 + threadIdx.x;   // 32 blocks
    int run = 0, mn = kM;
    for (int b = 0; b < NB; ++b) {
        const size_t o = (size_t)b * kP + p;
        const int h = histoff[o];
        histoff[o] = run;          // same-thread read-then-write: safe
        run += h;
        mn = min(mn, minb[o]);
    }
    cnt[p] = run;
    first[p] = mn;
}

// ---- k3: exclusive scan of cnt -> binstart; zero accum ----
__global__ __launch_bounds__(256)
void k3_scan(const int* __restrict__ cnt, int* __restrict__ binstart,
             float* __restrict__ accum) {
    __shared__ int part[256];
    const int t = threadIdx.x;
    constexpr int seg = kP / 256;   // 32
    int loc[seg];
    int s = 0;
    const int base = t * seg;
#pragma unroll
    for (int j = 0; j < seg; ++j) { loc[j] = s; s += cnt[base + j]; }
    part[t] = s;
    __syncthreads();
    if (t == 0) {
        int r = 0;
        for (int i = 0; i < 256; ++i) { const int v = part[i]; part[i] = r; r += v; }
    }
    __syncthreads();
    const int pb = part[t];
#pragma unroll
    for (int j = 0; j < seg; ++j) binstart[base + j] = pb + loc[j];
    if (t == 0) { accum[0] = 0.0f; accum[1] = 0.0f; }
}

// ---- k5v<CB>: scatter CB classes (bf16) into parcel-sorted rows ----
template <int CB>
__global__ __launch_bounds__(256)
void k5v(const int* __restrict__ target, const int* __restrict__ parcel,
         const float* __restrict__ pred, const int* __restrict__ off,
         const int* __restrict__ binstart, unsigned short* __restrict__ sortedV,
         int cbase) {
    __shared__ int cur[kP];
    const int b = blockIdx.x;
    const int* ob = off + (size_t)b * kP;
    for (int p = threadIdx.x; p < kP; p += 256) cur[p] = binstart[p] + ob[p];
    __syncthreads();
    const int base = b * CH;
    for (int j = threadIdx.x; j < CH; j += 256) {
        const int i = base + j;
        if (target[i] == kIgnore) continue;
        const int p = parcel[i];
        const int pos = atomicAdd(&cur[p], 1);   // LDS atomic, block-local
        const int n = i >> 18, hw = i & (kHW - 1);
        const float* pr = pred + (size_t)n * kC * kHW + (size_t)cbase * kHW + hw;
        float v[CB];
#pragma unroll
        for (int c = 0; c < CB; ++c) v[c] = pr[(size_t)c * kHW];
        unsigned w[CB / 2];
#pragma unroll
        for (int q = 0; q < CB / 2; ++q)
            w[q] = bf16rne(v[2 * q]) | (bf16rne(v[2 * q + 1]) << 16);
        unsigned short* dst = sortedV + (size_t)pos * CB;
        if constexpr (CB == 4) {
            *reinterpret_cast<uint2*>(dst) = make_uint2(w[0], w[1]);        // 8B, 8-aligned
        } else if constexpr (CB == 10) {
#pragma unroll
            for (int q = 0; q < 5; ++q)
                reinterpret_cast<unsigned*>(dst)[q] = w[q];                  // 20B, 4-aligned
        } else { // CB == 20
#pragma unroll
            for (int q = 0; q < 5; ++q)
                reinterpret_cast<uint2*>(dst)[q] = make_uint2(w[2*q], w[2*q+1]); // 40B, 8-aligned
        }
    }
}

// ---- k6v<CB>: wave-per-parcel coalesced reduce of sorted bf16 rows ----
template <int CB>
__global__ __launch_bounds__(256)
void k6v(const unsigned short* __restrict__ sortedV,
         const int* __restrict__ binstart, const int* __restrict__ cnt,
         float* __restrict__ pacc, int cbase) {
    const int wid = threadIdx.x >> 6, lane = threadIdx.x & 63;
    const int p = blockIdx.x * 4 + wid;
    const int c0 = binstart[p];
    const int n  = cnt[p];
    float acc[CB];
#pragma unroll
    for (int c = 0; c < CB; ++c) acc[c] = 0.0f;
    const unsigned short* base = sortedV + (size_t)c0 * CB;

    auto accum_row = [&](const unsigned short* row) {
        unsigned w[CB / 2];
        if constexpr (CB == 4) {
            const uint2 u = *reinterpret_cast<const uint2*>(row);
            w[0] = u.x; w[1] = u.y;
        } else if constexpr (CB == 10) {
#pragma unroll
            for (int q = 0; q < 5; ++q) w[q] = reinterpret_cast<const unsigned*>(row)[q];
        } else {
#pragma unroll
            for (int q = 0; q < 5; ++q) {
                const uint2 u = reinterpret_cast<const uint2*>(row)[q];
                w[2*q] = u.x; w[2*q+1] = u.y;
            }
        }
#pragma unroll
        for (int q = 0; q < CB / 2; ++q) {
            acc[2*q]   += __uint_as_float(w[q] << 16);
            acc[2*q+1] += __uint_as_float(w[q] & 0xffff0000u);
        }
    };

    int r = lane;
    for (; r + 64 < n; r += 128) {        // 2 rows in flight
        accum_row(base + (size_t)r * CB);
        accum_row(base + (size_t)(r + 64) * CB);
    }
    if (r < n) accum_row(base + (size_t)r * CB);

#pragma unroll
    for (int c = 0; c < CB; ++c) {
        float v = acc[c];
#pragma unroll
        for (int o = 32; o > 0; o >>= 1) v += __shfl_xor(v, o);
        acc[c] = v;
    }
    if (lane == 0) {
#pragma unroll
        for (int c = 0; c < CB; ++c) pacc[(size_t)p * kC + cbase + c] = acc[c];
    }
}

// ---- k_final: per-parcel balanced-softmax NLL, global mean ----
__global__ __launch_bounds__(256)
void k_final(const float* __restrict__ pacc, const int* __restrict__ cnt,
             const int* __restrict__ first, const int* __restrict__ target,
             const int* __restrict__ cls_num, float* __restrict__ accum) {
    __shared__ float logcls[kC];
    if (threadIdx.x < kC) logcls[threadIdx.x] = logf((float)cls_num[threadIdx.x]);
    __syncthreads();
    const int p = blockIdx.x * 256 + threadIdx.x;   // 32 blocks
    float nll = 0.0f, pres = 0.0f;
    const int n = cnt[p];
    if (n > 0) {
        int f = first[p]; if (f > kM - 1) f = kM - 1;
        const int label = target[f];
        const float inv = 1.0f / (float)n;
        float bal[kC]; float m = -3.402823466e38f;
#pragma unroll
        for (int c = 0; c < kC; ++c) {
            bal[c] = pacc[(size_t)p * kC + c] * inv + logcls[c];
            m = fmaxf(m, bal[c]);
        }
        float s = 0.0f;
#pragma unroll
        for (int c = 0; c < kC; ++c) s += expf(bal[c] - m);
        const float lse = m + logf(s);
        pres = 1.0f;
        if (label >= 0 && label < kC) nll = lse - bal[label];
    }
    float a = nll, b = pres;
#pragma unroll
    for (int o = 32; o > 0; o >>= 1) { a += __shfl_down(a, o); b += __shfl_down(b, o); }
    __shared__ float wsum[4], wcnt[4];
    const int lane = threadIdx.x & 63, wid = threadIdx.x >> 6;
    if (lane == 0) { wsum[wid] = a; wcnt[wid] = b; }
    __syncthreads();
    if (threadIdx.x == 0) {
        float sa = 0.0f, sb = 0.0f;
        for (int w = 0; w < 4; ++w) { sa += wsum[w]; sb += wcnt[w]; }
        atomicAdd(&accum[0], sa);
        atomicAdd(&accum[1], sb);
    }
}

__global__ void k7_out(const float* __restrict__ accum, float* __restrict__ out) {
    out[0] = accum[0] / fmaxf(accum[1], 1.0f);
}

// ---- atomic fallback (proven round-2 path; only for tiny ws, never expected) ----
__global__ __launch_bounds__(256)
void fb_init(float* seg, float* cnt, int* first, float* accum) {
    const int i = blockIdx.x * blockDim.x + threadIdx.x;
    if (i < kP * kC) seg[i] = 0.0f;
    if (i < kP) { cnt[i] = 0.0f; first[i] = kM; }
    if (i < 2) accum[i] = 0.0f;
}
__global__ __launch_bounds__(256)
void fb_scatter(const float* __restrict__ pred, const int* __restrict__ target,
                const int* __restrict__ parcel, float* seg, float* cnt, int* first) {
    const int stride = gridDim.x * blockDim.x;
    for (int idx = blockIdx.x * blockDim.x + threadIdx.x; idx < kM; idx += stride) {
        const int t = target[idx];
        if (t == kIgnore) continue;
        const int p = parcel[idx];
        const int n = idx >> 18, hw = idx & (kHW - 1);
        const float* base = pred + (size_t)n * kC * kHW + hw;
        float* srow = seg + p * kC;
#pragma unroll
        for (int c = 0; c < kC; ++c) atomicAdd(&srow[c], base[(size_t)c * kHW]);
        atomicAdd(&cnt[p], 1.0f);
        atomicMin(&first[p], idx);
    }
}
__global__ __launch_bounds__(256)
void fb_finalize(const float* __restrict__ seg, const float* __restrict__ cnt,
                 const int* __restrict__ first, const int* __restrict__ target,
                 const int* __restrict__ cls_num, float* __restrict__ accum) {
    __shared__ float logcls[kC];
    if (threadIdx.x < kC) logcls[threadIdx.x] = logf((float)cls_num[threadIdx.x]);
    __syncthreads();
    const int p = blockIdx.x * blockDim.x + threadIdx.x;
    float nll = 0.0f, pres = 0.0f;
    if (p < kP) {
        const float c = cnt[p];
        if (c > 0.0f) {
            int f = first[p]; if (f > kM - 1) f = kM - 1;
            const int label = target[f];
            const float inv = 1.0f / c;
            float bal[kC]; float m = -3.402823466e38f;
#pragma unroll
            for (int k = 0; k < kC; ++k) {
                bal[k] = seg[p * kC + k] * inv + logcls[k];
                m = fmaxf(m, bal[k]);
            }
            float s = 0.0f;
#pragma unroll
            for (int k = 0; k < kC; ++k) s += expf(bal[k] - m);
            const float lse = m + logf(s);
            pres = 1.0f;
            if (label >= 0 && label < kC) nll = lse - bal[label];
        }
    }
    float a = nll, b = pres;
#pragma unroll
    for (int o = 32; o > 0; o >>= 1) { a += __shfl_down(a, o); b += __shfl_down(b, o); }
    __shared__ float wsum[4], wcnt[4];
    const int lane = threadIdx.x & 63, wid = threadIdx.x >> 6;
    if (lane == 0) { wsum[wid] = a; wcnt[wid] = b; }
    __syncthreads();
    if (threadIdx.x == 0) {
        float sa = 0.0f, sb = 0.0f;
        for (int w = 0; w < 4; ++w) { sa += wsum[w]; sb += wcnt[w]; }
        atomicAdd(&accum[0], sa);
        atomicAdd(&accum[1], sb);
    }
}

// ---- launch ----
extern "C" void kernel_launch(void* const* d_in, const int* in_sizes, int n_in,
                              void* d_out, int out_size, void* d_ws, size_t ws_size,
                              hipStream_t stream) {
    const float* pred    = (const float*)d_in[0];
    const int*   target  = (const int*)d_in[1];
    const int*   parcel  = (const int*)d_in[2];
    const int*   cls_num = (const int*)d_in[3];
    char* ws = (char*)d_ws;

    if (ws_size >= kNeed4) {
        int*   off      = (int*)(ws + oOff);
        int*   cnt      = (int*)(ws + oCnt);
        int*   first    = (int*)(ws + oFirst);
        int*   binstart = (int*)(ws + oBin);
        float* accum    = (float*)(ws + oAcc);
        float* pacc     = (float*)(ws + oPAcc);
        int*   minb     = (int*)(ws + oMinb);
        unsigned short* sortedV = (unsigned short*)(ws + oSort);

        k1_hist<<<NB, 256, 0, stream>>>(target, parcel, off, minb);
        k2_colscan<<<kP / 256, 256, 0, stream>>>(off, minb, cnt, first);
        k3_scan<<<1, 256, 0, stream>>>(cnt, binstart, accum);

        if (ws_size >= kNeed20) {
            k5v<20><<<NB, 256, 0, stream>>>(target, parcel, pred, off, binstart, sortedV, 0);
            k6v<20><<<kP / 4, 256, 0, stream>>>(sortedV, binstart, cnt, pacc, 0);
        } else if (ws_size >= kNeed10) {
            for (int g = 0; g < 2; ++g) {
                k5v<10><<<NB, 256, 0, stream>>>(target, parcel, pred, off, binstart, sortedV, g * 10);
                k6v<10><<<kP / 4, 256, 0, stream>>>(sortedV, binstart, cnt, pacc, g * 10);
            }
        } else {
            for (int g = 0; g < 5; ++g) {
                k5v<4><<<NB, 256, 0, stream>>>(target, parcel, pred, off, binstart, sortedV, g * 4);
                k6v<4><<<kP / 4, 256, 0, stream>>>(sortedV, binstart, cnt, pacc, g * 4);
            }
        }
        k_final<<<kP / 256, 256, 0, stream>>>(pacc, cnt, first, target, cls_num, accum);
        k7_out<<<1, 1, 0, stream>>>(accum, (float*)d_out);
    } else {
        float* seg   = (float*)(ws);
        float* cnt   = (float*)(ws + (size_t)kP * kC * 4);
        int*   first = (int*)(ws + (size_t)kP * kC * 4 + (size_t)kP * 4);
        float* accum = (float*)(ws + (size_t)kP * kC * 4 + (size_t)kP * 8);
        fb_init<<<(kP * kC + 255) / 256, 256, 0, stream>>>(seg, cnt, first, accum);
        fb_scatter<<<2048, 256, 0, stream>>>(pred, target, parcel, seg, cnt, first);
        fb_finalize<<<kP / 256, 256, 0, stream>>>(seg, cnt, first, target, cls_num, accum);
        k7_out<<<1, 1, 0, stream>>>(accum, (float*)d_out);
    }
}